// Round 1
// baseline (1740.461 us; speedup 1.0000x reference)
//
#include <hip/hip_runtime.h>

// MovingNCA on MI355X — factorized recurrence.
//
// Key identity: outputs[n,m,k] = sigmoid(c*w0[k] + p*w1[k] + ob[k]) where
//   c = comms[n,m] (3x3x96 conv of accumulated state), p = percep[n,m] (scalar).
// Since state accumulates sigmoid outputs and the conv is linear, we track the
// conv value C[n,m] directly:
//   C_{t+1}[n,m] = C_t[n,m] + sum_{i,j} g_{i,j}(n+i-1, m+j-1)
//   g_q(n',m')   = sum_{k<96} s_k(n',m') * cw[q][k],  q = i*3+j
// G planes are zero-padded (512x512, cell (n,m) at [(n+1)*512+(m+1)]) so the
// gather needs no bounds checks. Class-channel sums are deferred: store (c,p)
// per cell per iter, recompute the 32 class sigmoids in a final kernel
// (saves 66 MB/iter of HBM read-modify-write).

#define NIMG   512
#define NNEO   510
#define NCELL  (NNEO * NNEO)
#define PLANE  (NIMG * NIMG)
#define NITERS 50
#define CLIPHI 509
#define NCA_THRESH 0.0007f

__device__ __forceinline__ float fast_sigmoid(float x) {
#if __has_builtin(__builtin_amdgcn_exp2f) && __has_builtin(__builtin_amdgcn_rcpf)
    float e = __builtin_amdgcn_exp2f(x * -1.44269504088896341f);
    return __builtin_amdgcn_rcpf(1.0f + e);
#else
    return 1.0f / (1.0f + __expf(-x));
#endif
}

// One NCA iteration. Uniform weight reads -> scalar loads on the scalar pipe.
__global__ __launch_bounds__(256) void nca_iter(
    const float* __restrict__ img,    // [512*512]
    const float* __restrict__ cw,     // comms_w [9][96] (i*3+j major, k minor)
    const float* __restrict__ cb,     // [1]
    const float* __restrict__ pw,     // perc_w [9]
    const float* __restrict__ pb,     // [1]
    const float* __restrict__ ow,     // out_w w11 [2][98]
    const float* __restrict__ ob,     // out_b [98]
    float*       __restrict__ C,      // [NCELL] running conv value
    unsigned*    __restrict__ perc,   // [NCELL] packed (x<<16)|y
    const float* __restrict__ Gprev,  // [9][PLANE]
    float*       __restrict__ Gcur,   // [9][PLANE]
    float2*      __restrict__ hist_t, // [NCELL] (c,p) for this iter, or null
    float*       __restrict__ outAcc, // d_out RMW fallback, or null
    int t)
{
    const int m = blockIdx.x * 64 + (threadIdx.x & 63);
    const int n = blockIdx.y * 4  + (threadIdx.x >> 6);
    if (m >= NNEO || n >= NNEO) return;
    const int cell = n * NNEO + m;

    // ---- perception position (perc from previous iter; t=0: (n,m)) ----
    int x, y;
    if (t == 0) { x = n; y = m; }
    else { unsigned pk = perc[cell]; x = (int)(pk >> 16); y = (int)(pk & 0xffffu); }

    // ---- p = 3x3 img window . perc_w + perc_b ----
    float p = pb[0];
    #pragma unroll
    for (int i = 0; i < 3; ++i)
        #pragma unroll
        for (int j = 0; j < 3; ++j)
            p = fmaf(img[(x + i) * NIMG + (y + j)], pw[i * 3 + j], p);

    // ---- c = running conv + gathered deltas from previous iter ----
    float cconv = 0.0f;
    if (t > 0) {
        cconv = C[cell];
        #pragma unroll
        for (int i = 0; i < 3; ++i)
            #pragma unroll
            for (int j = 0; j < 3; ++j)
                cconv += Gprev[(i * 3 + j) * PLANE + (n + i) * NIMG + (m + j)];
    }
    C[cell] = cconv;
    const float c = cconv + cb[0];

    if (hist_t) hist_t[cell] = make_float2(c, p);

    // ---- 96 sigmoids + 9 projections g_q = sum_k s_k * cw[q][k] ----
    float g[9] = {0.f, 0.f, 0.f, 0.f, 0.f, 0.f, 0.f, 0.f, 0.f};
    #pragma unroll
    for (int kb = 0; kb < 96; kb += 16) {
        float s[16];
        #pragma unroll
        for (int u = 0; u < 16; ++u) {
            const int k = kb + u;
            s[u] = fast_sigmoid(fmaf(c, ow[k], fmaf(p, ow[98 + k], ob[k])));
        }
        if (outAcc && kb >= 64) {   // fallback path: direct class accumulation
            #pragma unroll
            for (int u = 0; u < 16; ++u) {
                const int k = kb + u;
                outAcc[(size_t)cell * 32 + (k - 64)] += s[u];
            }
        }
        #pragma unroll
        for (int q = 0; q < 9; ++q) {
            float a = g[q];
            #pragma unroll
            for (int u = 0; u < 16; ++u)
                a = fmaf(s[u], cw[q * 96 + kb + u], a);
            g[q] = a;
        }
    }
    #pragma unroll
    for (int q = 0; q < 9; ++q)
        Gcur[q * PLANE + (n + 1) * NIMG + (m + 1)] = g[q];

    // ---- action channels 96,97 -> perc update ----
    const float s96 = fast_sigmoid(fmaf(c, ow[96], fmaf(p, ow[98 + 96], ob[96])));
    const float s97 = fast_sigmoid(fmaf(c, ow[97], fmaf(p, ow[98 + 97], ob[97])));
    int dx = (s96 < -NCA_THRESH) ? -1 : ((s96 > NCA_THRESH) ? 1 : 0);
    int dy = (s97 < -NCA_THRESH) ? -1 : ((s97 > NCA_THRESH) ? 1 : 0);
    x = min(max(x + dx, 0), CLIPHI);
    y = min(max(y + dy, 0), CLIPHI);
    perc[cell] = ((unsigned)x << 16) | (unsigned)y;
}

// Deferred class accumulation: out[cell][k] = sum_t sigmoid(c_t*w0[64+k] + p_t*w1[64+k] + ob[64+k])
__global__ __launch_bounds__(256) void nca_final(
    const float2* __restrict__ hist,  // [NITERS][NCELL]
    const float* __restrict__ ow,
    const float* __restrict__ ob,
    float* __restrict__ out)          // [NCELL][32]
{
    const int cell = blockIdx.x * 256 + threadIdx.x;
    if (cell >= NCELL) return;
    float acc[32];
    #pragma unroll
    for (int k = 0; k < 32; ++k) acc[k] = 0.0f;
    for (int t = 0; t < NITERS; ++t) {
        const float2 cp = hist[(size_t)t * NCELL + cell];
        #pragma unroll
        for (int k = 0; k < 32; ++k)
            acc[k] += fast_sigmoid(fmaf(cp.x, ow[64 + k], fmaf(cp.y, ow[98 + 64 + k], ob[64 + k])));
    }
    float4* o4 = (float4*)(out + (size_t)cell * 32);
    #pragma unroll
    for (int v = 0; v < 8; ++v)
        o4[v] = make_float4(acc[4 * v], acc[4 * v + 1], acc[4 * v + 2], acc[4 * v + 3]);
}

extern "C" void kernel_launch(void* const* d_in, const int* in_sizes, int n_in,
                              void* d_out, int out_size, void* d_ws, size_t ws_size,
                              hipStream_t stream) {
    const float* img = (const float*)d_in[0];
    const float* cw  = (const float*)d_in[1];
    const float* cb  = (const float*)d_in[2];
    const float* pw  = (const float*)d_in[3];
    const float* pb  = (const float*)d_in[4];
    const float* ow  = (const float*)d_in[5];
    const float* ob  = (const float*)d_in[6];
    float* out = (float*)d_out;

    // ws layout (bytes)
    char* ws = (char*)d_ws;
    const size_t gBytes   = (size_t)9 * PLANE * 4;          // 9,437,184 per buffer
    const size_t cOff     = 2 * gBytes;                     // 18,874,368
    const size_t percOff  = cOff + (size_t)NCELL * 4;       // +1,040,400
    const size_t histOff  = percOff + (size_t)NCELL * 4;    // +1,040,400
    const size_t histBytes = (size_t)NITERS * NCELL * 8;    // 104,040,000
    const size_t needHist = histOff + histBytes;

    float*    G[2] = { (float*)(ws), (float*)(ws + gBytes) };
    float*    C    = (float*)(ws + cOff);
    unsigned* perc = (unsigned*)(ws + percOff);
    float2*   hist = (float2*)(ws + histOff);

    const bool useHist = (ws_size >= needHist);

    // Zero G planes (borders must be 0; ws is poisoned before every call).
    hipMemsetAsync(ws, 0, 2 * gBytes, stream);
    if (!useHist) hipMemsetAsync(out, 0, (size_t)out_size * 4, stream);

    dim3 block(256, 1, 1);
    dim3 grid(8, 128, 1);  // 8*64 = 512 cols, 128*4 = 512 rows (masked to 510)
    for (int t = 0; t < NITERS; ++t) {
        nca_iter<<<grid, block, 0, stream>>>(
            img, cw, cb, pw, pb, ow, ob, C, perc,
            G[(t + 1) & 1], G[t & 1],
            useHist ? (hist + (size_t)t * NCELL) : (float2*)nullptr,
            useHist ? (float*)nullptr : out,
            t);
    }
    if (useHist) {
        nca_final<<<dim3((NCELL + 255) / 256, 1, 1), block, 0, stream>>>(hist, ow, ob, out);
    }
}